// Round 5
// baseline (1428.691 us; speedup 1.0000x reference)
//
#include <hip/hip_runtime.h>

typedef __attribute__((ext_vector_type(8))) short bf16x8;
typedef __attribute__((ext_vector_type(4))) float f32x4;
typedef __attribute__((ext_vector_type(4))) unsigned short u16x4;

#define MFMA __builtin_amdgcn_mfma_f32_16x16x32_bf16

__device__ __forceinline__ unsigned short f2bf(float x) {
    union { float f; unsigned u; } v; v.f = x;
    unsigned r = v.u + 0x7FFFu + ((v.u >> 16) & 1u);
    return (unsigned short)(r >> 16);
}
__device__ __forceinline__ float bf2f(unsigned short h) {
    union { unsigned u; float f; } v; v.u = ((unsigned)h) << 16;
    return v.f;
}
// packed bf16 atomic add, device scope (sc1) so cross-XCD updates are coherent
__device__ __forceinline__ void atom_pk_bf16(unsigned short* p, unsigned v2) {
    asm volatile("global_atomic_pk_add_bf16 %0, %1, off sc1" :: "v"(p), "v"(v2) : "memory");
}

// ===========================================================================
// Pack weights into MFMA B-fragment layout, bf16 hi/lo.
// Regions (shorts): pkc_h(64*512) pkc_l | pkm_h(32*512) pkm_l |
//                   pk1b_h(96*512) pk1b_l | pk2a_h(32*512) pk2a_l |
//                   pk2b_h(32*512) pk2b_l      (total 512*512 shorts = 512KB)
// ===========================================================================
__global__ void pack_new(const float* __restrict__ w1a, const float* __restrict__ w1b,
                         const float* __restrict__ w2a, const float* __restrict__ w2b,
                         unsigned short* __restrict__ pk)
{
    const int b = blockIdx.x, l = threadIdx.x;
    unsigned short* ph;
    unsigned short* pl;
    int tile;
    bf16x8 hv, lv;

    if (b < 64) {            // cat: [W_top | W_bot], 4kc x 16ct
        tile = b;
        ph = pk; pl = pk + 64 * 512;
        int kc = tile >> 4, ct = tile & 15;
#pragma unroll
        for (int j = 0; j < 8; ++j) {
            int k = kc * 32 + (l >> 4) * 8 + j;
            int n = ct * 16 + (l & 15);
            float v = (n < 128) ? w1a[(size_t)k * 128 + n]
                                : w1a[(size_t)(256 + k) * 128 + (n - 128)];
            unsigned short h = f2bf(v);
            hv[j] = (short)h; lv[j] = (short)f2bf(v - bf2f(h));
        }
    } else if (b < 96) {     // mid: 4kc x 8ct
        tile = b - 64;
        ph = pk + 2 * 64 * 512; pl = ph + 32 * 512;
        int kc = tile >> 3, ct = tile & 7;
#pragma unroll
        for (int j = 0; j < 8; ++j) {
            int k = kc * 32 + (l >> 4) * 8 + j;
            int n = ct * 16 + (l & 15);
            float v = w1a[(size_t)(128 + k) * 128 + n];
            unsigned short h = f2bf(v);
            hv[j] = (short)h; lv[j] = (short)f2bf(v - bf2f(h));
        }
    } else if (b < 192) {    // w1b: 4kc x 24ct
        tile = b - 96;
        ph = pk + 2 * 64 * 512 + 2 * 32 * 512; pl = ph + 96 * 512;
        int kc = tile / 24, ct = tile % 24;
#pragma unroll
        for (int j = 0; j < 8; ++j) {
            int k = kc * 32 + (l >> 4) * 8 + j;
            int n = ct * 16 + (l & 15);
            float v = w1b[(size_t)k * 384 + n];
            unsigned short h = f2bf(v);
            hv[j] = (short)h; lv[j] = (short)f2bf(v - bf2f(h));
        }
    } else if (b < 224) {    // w2a
        tile = b - 192;
        ph = pk + 2 * 64 * 512 + 2 * 32 * 512 + 2 * 96 * 512; pl = ph + 32 * 512;
        int kc = tile >> 3, ct = tile & 7;
#pragma unroll
        for (int j = 0; j < 8; ++j) {
            int k = kc * 32 + (l >> 4) * 8 + j;
            int n = ct * 16 + (l & 15);
            float v = w2a[(size_t)k * 128 + n];
            unsigned short h = f2bf(v);
            hv[j] = (short)h; lv[j] = (short)f2bf(v - bf2f(h));
        }
    } else {                 // w2b
        tile = b - 224;
        ph = pk + 2 * 64 * 512 + 2 * 32 * 512 + 2 * 96 * 512 + 2 * 32 * 512; pl = ph + 32 * 512;
        int kc = tile >> 3, ct = tile & 7;
#pragma unroll
        for (int j = 0; j < 8; ++j) {
            int k = kc * 32 + (l >> 4) * 8 + j;
            int n = ct * 16 + (l & 15);
            float v = w2b[(size_t)k * 128 + n];
            unsigned short h = f2bf(v);
            hv[j] = (short)h; lv[j] = (short)f2bf(v - bf2f(h));
        }
    }
    *(bf16x8*)&ph[(size_t)(tile * 64 + l) * 8] = hv;
    *(bf16x8*)&pl[(size_t)(tile * 64 + l) * 8] = lv;
}

// ===========================================================================
// Precompute A_tb = obj @ [W_top | W_bot]  (O x 256, stored BF16).
// Epilogue packs lane pairs via shfl_xor into dword stores.
// ===========================================================================
__global__ __launch_bounds__(512, 4) void obj_pre_kernel(
    const float* __restrict__ obj,
    const unsigned short* __restrict__ pkc_h, const unsigned short* __restrict__ pkc_l,
    unsigned short* __restrict__ A_tb, int O)
{
    __shared__ __align__(16) unsigned short Xh[64 * 128];
    __shared__ __align__(16) unsigned short Xl[64 * 128];

    const int tid = threadIdx.x;
    const int w = tid >> 6, l = tid & 63;
    const int rh = w & 1, cg = w >> 1;
    const int r0 = blockIdx.x * 64;

#pragma unroll
    for (int it = 0; it < 4; ++it) {
        int q = it * 512 + tid;
        int row = q >> 5, c4 = (q & 31) * 4;
        int rg = r0 + row; if (rg > O - 1) rg = O - 1;
        float4 v = *(const float4*)&obj[(size_t)rg * 128 + c4];
        u16x4 hv, lv; unsigned short h;
        h = f2bf(v.x); hv[0] = h; lv[0] = f2bf(v.x - bf2f(h));
        h = f2bf(v.y); hv[1] = h; lv[1] = f2bf(v.y - bf2f(h));
        h = f2bf(v.z); hv[2] = h; lv[2] = f2bf(v.z - bf2f(h));
        h = f2bf(v.w); hv[3] = h; lv[3] = f2bf(v.w - bf2f(h));
        int pc = row * 128 + (c4 ^ ((row & 7) << 3));
        *(u16x4*)&Xh[pc] = hv;
        *(u16x4*)&Xl[pc] = lv;
    }
    __syncthreads();

    f32x4 acc[2][4];
#pragma unroll
    for (int i = 0; i < 2; ++i)
#pragma unroll
        for (int j = 0; j < 4; ++j) acc[i][j] = (f32x4)0.0f;

#pragma unroll
    for (int kc = 0; kc < 4; ++kc) {
        bf16x8 ah[2], al[2];
#pragma unroll
        for (int rt = 0; rt < 2; ++rt) {
            int row = (rh * 2 + rt) * 16 + (l & 15);
            int col0 = kc * 32 + (l >> 4) * 8;
            int pc = row * 128 + (col0 ^ ((row & 7) << 3));
            ah[rt] = *(const bf16x8*)&Xh[pc];
            al[rt] = *(const bf16x8*)&Xl[pc];
        }
#pragma unroll
        for (int ct = 0; ct < 4; ++ct) {
            const int tile = kc * 16 + cg * 4 + ct;
            bf16x8 bh = *(const bf16x8*)&pkc_h[(size_t)(tile * 64 + l) * 8];
            bf16x8 bl = *(const bf16x8*)&pkc_l[(size_t)(tile * 64 + l) * 8];
#pragma unroll
            for (int rt = 0; rt < 2; ++rt) {
                acc[rt][ct] = MFMA(ah[rt], bh, acc[rt][ct], 0, 0, 0);
                acc[rt][ct] = MFMA(ah[rt], bl, acc[rt][ct], 0, 0, 0);
                acc[rt][ct] = MFMA(al[rt], bh, acc[rt][ct], 0, 0, 0);
            }
        }
    }

    // store bf16, lane-pair packed into dwords
#pragma unroll
    for (int ct = 0; ct < 4; ++ct) {
        int col = cg * 64 + ct * 16 + (l & 15);
        int cb = col & ~1;
#pragma unroll
        for (int rt = 0; rt < 2; ++rt) {
            float v[4], p[4];
#pragma unroll
            for (int r = 0; r < 4; ++r) v[r] = acc[rt][ct][r];
#pragma unroll
            for (int r = 0; r < 4; ++r) p[r] = __shfl_xor(v[r], 1, 64);
            int base = (rh * 2 + rt) * 16 + (l >> 4) * 4;
#pragma unroll
            for (int k = 0; k < 2; ++k) {
                int rr = (l & 1) * 2 + k;
                int row = base + rr;
                float lo = (l & 1) ? p[rr] : v[rr];
                float hi = (l & 1) ? v[rr] : p[rr];
                unsigned u = (unsigned)f2bf(lo) | ((unsigned)f2bf(hi) << 16);
                if (r0 + row < O)
                    *(unsigned*)&A_tb[(size_t)(r0 + row) * 256 + cb] = u;
            }
        }
    }
}

// ===========================================================================
// Triple kernel: G = A_top[s]+A_bot[o]+b1a -> acc init; GEMM1 = predi@W_mid;
// GEMM2; scatter via packed-bf16 atomics to pooled (bf16), new_p f32.
// ===========================================================================
__global__ __launch_bounds__(512, 8) void triple_mlp_mfma2(
    const unsigned short* __restrict__ A_tb, const float* __restrict__ predi,
    const int* __restrict__ edges,
    const float* __restrict__ b1a, const float* __restrict__ b1b,
    const unsigned short* __restrict__ pkm_h, const unsigned short* __restrict__ pkm_l,
    const unsigned short* __restrict__ pk1b_h, const unsigned short* __restrict__ pk1b_l,
    unsigned short* __restrict__ pooled, float* __restrict__ out_p,
    float* __restrict__ counts, int T)
{
    __shared__ __align__(16) char SB[64 * 132 * 4];
    float (*G)[132] = (float (*)[132])SB;
    unsigned short* Xh = (unsigned short*)SB;
    unsigned short* Xl = (unsigned short*)(SB + 64 * 128 * 2);
    __shared__ int sIdx[64], oIdx[64];

    const int tid = threadIdx.x;
    const int w = tid >> 6, l = tid & 63;
    const int rh = w & 1, cg = w >> 1;
    const int t0 = blockIdx.x * 64;

    if (tid < 64) {
        int t = t0 + tid; int tc = (t < T) ? t : (T - 1);
        sIdx[tid] = edges[2 * tc];
        oIdx[tid] = edges[2 * tc + 1];
    }
    __syncthreads();

    if (tid < 64)        { if (t0 + tid      < T) atomicAdd(&counts[sIdx[tid]],      1.0f); }
    else if (tid < 128)  { if (t0 + tid - 64 < T) atomicAdd(&counts[oIdx[tid - 64]], 1.0f); }

    // ---- stage G = A_top[s] + A_bot[o] + b1a (f32, pad 132) ----
#pragma unroll
    for (int it = 0; it < 2; ++it) {
        int q = it * 512 + tid;
        int row = q >> 4, c8 = (q & 15) * 8;
        bf16x8 a = *(const bf16x8*)&A_tb[(size_t)sIdx[row] * 256 + c8];
        bf16x8 b = *(const bf16x8*)&A_tb[(size_t)oIdx[row] * 256 + 128 + c8];
        float bb[8];
        *(float4*)&bb[0] = *(const float4*)&b1a[c8];
        *(float4*)&bb[4] = *(const float4*)&b1a[c8 + 4];
        float g[8];
#pragma unroll
        for (int j = 0; j < 8; ++j)
            g[j] = bf2f((unsigned short)a[j]) + bf2f((unsigned short)b[j]) + bb[j];
        *(float4*)&G[row][c8]     = *(float4*)&g[0];
        *(float4*)&G[row][c8 + 4] = *(float4*)&g[4];
    }
    __syncthreads();

    // ---- init acc1 from G (C-fragment layout) ----
    f32x4 acc1[2][2];
#pragma unroll
    for (int rt = 0; rt < 2; ++rt)
#pragma unroll
        for (int c2 = 0; c2 < 2; ++c2) {
            int col = cg * 32 + c2 * 16 + (l & 15);
#pragma unroll
            for (int r = 0; r < 4; ++r) {
                int row = (rh * 2 + rt) * 16 + (l >> 4) * 4 + r;
                acc1[rt][c2][r] = G[row][col];
            }
        }
    __syncthreads();   // G dead; Xh/Xl reuse same LDS

    // ---- stage predi -> Xh/Xl (bf16 hi/lo, swizzled) ----
#pragma unroll
    for (int it = 0; it < 4; ++it) {
        int q = it * 512 + tid;
        int row = q >> 5, c4 = (q & 31) * 4;
        int t = t0 + row; int tc = (t < T) ? t : (T - 1);
        float4 v = *(const float4*)&predi[(size_t)tc * 128 + c4];
        u16x4 hv, lv; unsigned short h;
        h = f2bf(v.x); hv[0] = h; lv[0] = f2bf(v.x - bf2f(h));
        h = f2bf(v.y); hv[1] = h; lv[1] = f2bf(v.y - bf2f(h));
        h = f2bf(v.z); hv[2] = h; lv[2] = f2bf(v.z - bf2f(h));
        h = f2bf(v.w); hv[3] = h; lv[3] = f2bf(v.w - bf2f(h));
        int pc = row * 128 + (c4 ^ ((row & 7) << 3));
        *(u16x4*)&Xh[pc] = hv;
        *(u16x4*)&Xl[pc] = lv;
    }
    __syncthreads();

    // ---- GEMM1: acc1 += predi @ W_mid ----
#pragma unroll
    for (int kc = 0; kc < 4; ++kc) {
        bf16x8 ah[2], al[2];
#pragma unroll
        for (int rt = 0; rt < 2; ++rt) {
            int row = (rh * 2 + rt) * 16 + (l & 15);
            int col0 = kc * 32 + (l >> 4) * 8;
            int pc = row * 128 + (col0 ^ ((row & 7) << 3));
            ah[rt] = *(const bf16x8*)&Xh[pc];
            al[rt] = *(const bf16x8*)&Xl[pc];
        }
#pragma unroll
        for (int c2 = 0; c2 < 2; ++c2) {
            const int tile = kc * 8 + cg * 2 + c2;
            bf16x8 bh = *(const bf16x8*)&pkm_h[(size_t)(tile * 64 + l) * 8];
            bf16x8 bl = *(const bf16x8*)&pkm_l[(size_t)(tile * 64 + l) * 8];
#pragma unroll
            for (int rt = 0; rt < 2; ++rt) {
                acc1[rt][c2] = MFMA(ah[rt], bh, acc1[rt][c2], 0, 0, 0);
                acc1[rt][c2] = MFMA(ah[rt], bl, acc1[rt][c2], 0, 0, 0);
                acc1[rt][c2] = MFMA(al[rt], bh, acc1[rt][c2], 0, 0, 0);
            }
        }
    }
    __syncthreads();

    // ---- H = relu(acc1) -> Xh/Xl ----
#pragma unroll
    for (int c2 = 0; c2 < 2; ++c2) {
        int col = cg * 32 + c2 * 16 + (l & 15);
#pragma unroll
        for (int rt = 0; rt < 2; ++rt) {
#pragma unroll
            for (int r = 0; r < 4; ++r) {
                int row = (rh * 2 + rt) * 16 + (l >> 4) * 4 + r;
                float h = fmaxf(acc1[rt][c2][r], 0.0f);
                unsigned short hh = f2bf(h);
                unsigned short hl = f2bf(h - bf2f(hh));
                int pc = row * 128 + (col ^ ((row & 7) << 3));
                Xh[pc] = hh; Xl[pc] = hl;
            }
        }
    }
    __syncthreads();

    // ---- GEMM2: H @ w1b (128x384) ----
    f32x4 acc2[2][6];
#pragma unroll
    for (int i = 0; i < 2; ++i)
#pragma unroll
        for (int j = 0; j < 6; ++j) acc2[i][j] = (f32x4)0.0f;

#pragma unroll
    for (int kc = 0; kc < 4; ++kc) {
        bf16x8 ah[2], al[2];
#pragma unroll
        for (int rt = 0; rt < 2; ++rt) {
            int row = (rh * 2 + rt) * 16 + (l & 15);
            int col0 = kc * 32 + (l >> 4) * 8;
            int pc = row * 128 + (col0 ^ ((row & 7) << 3));
            ah[rt] = *(const bf16x8*)&Xh[pc];
            al[rt] = *(const bf16x8*)&Xl[pc];
        }
#pragma unroll
        for (int ct = 0; ct < 6; ++ct) {
            const int tile = kc * 24 + cg * 6 + ct;
            bf16x8 bh = *(const bf16x8*)&pk1b_h[(size_t)(tile * 64 + l) * 8];
            bf16x8 bl = *(const bf16x8*)&pk1b_l[(size_t)(tile * 64 + l) * 8];
#pragma unroll
            for (int rt = 0; rt < 2; ++rt) {
                acc2[rt][ct] = MFMA(ah[rt], bh, acc2[rt][ct], 0, 0, 0);
                acc2[rt][ct] = MFMA(ah[rt], bl, acc2[rt][ct], 0, 0, 0);
                acc2[rt][ct] = MFMA(al[rt], bh, acc2[rt][ct], 0, 0, 0);
            }
        }
    }

    // ---- epilogue: cols 0-127 -> pk-atomic s, 128-255 -> new_p, 256-383 -> pk-atomic o
#pragma unroll
    for (int ct = 0; ct < 6; ++ct) {
        int col = cg * 96 + ct * 16 + (l & 15);
        float bb = b1b[col];
#pragma unroll
        for (int rt = 0; rt < 2; ++rt) {
            float v[4];
#pragma unroll
            for (int r = 0; r < 4; ++r) v[r] = fmaxf(acc2[rt][ct][r] + bb, 0.0f);
            int base = (rh * 2 + rt) * 16 + (l >> 4) * 4;
            if (col >= 128 && col < 256) {
#pragma unroll
                for (int r = 0; r < 4; ++r) {
                    int row = base + r;
                    if (t0 + row < T)
                        out_p[(size_t)(t0 + row) * 128 + (col - 128)] = v[r];
                }
            } else {
                float p[4];
#pragma unroll
                for (int r = 0; r < 4; ++r) p[r] = __shfl_xor(v[r], 1, 64);
                const int* IDX = (col < 128) ? sIdx : oIdx;
                int cb = ((col < 128) ? col : col - 256) & ~1;
#pragma unroll
                for (int k = 0; k < 2; ++k) {
                    int rr = (l & 1) * 2 + k;
                    int row = base + rr;
                    float lo = (l & 1) ? p[rr] : v[rr];
                    float hi = (l & 1) ? v[rr] : p[rr];
                    unsigned u = (unsigned)f2bf(lo) | ((unsigned)f2bf(hi) << 16);
                    if (t0 + row < T)
                        atom_pk_bf16(pooled + (size_t)IDX[row] * 128 + cb, u);
                }
            }
        }
    }
}

// ===========================================================================
// Object MLP: reads pooled (bf16) / counts, writes new_obj (f32) to d_out.
// ===========================================================================
__global__ __launch_bounds__(512, 8) void obj_mlp_mfma(
    const float* __restrict__ b2a, const float* __restrict__ b2b,
    const unsigned short* __restrict__ pk2a_h, const unsigned short* __restrict__ pk2a_l,
    const unsigned short* __restrict__ pk2b_h, const unsigned short* __restrict__ pk2b_l,
    const unsigned short* __restrict__ pooled, const float* __restrict__ counts,
    float* __restrict__ out, int O)
{
    __shared__ __align__(16) unsigned short Xh[64 * 128];
    __shared__ __align__(16) unsigned short Xl[64 * 128];

    const int tid = threadIdx.x;
    const int w = tid >> 6, l = tid & 63;
    const int rh = w & 1, cg = w >> 1;
    const int r0 = blockIdx.x * 64;

    // stage pooled(bf16)/counts -> normalized x, hi/lo swizzled
#pragma unroll
    for (int it = 0; it < 2; ++it) {
        int q = it * 512 + tid;
        int row = q >> 4, c8 = (q & 15) * 8;
        int rg = r0 + row; if (rg > O - 1) rg = O - 1;
        float c = counts[rg];
        c = fminf(fmaxf(c, 1.0f), 1000.0f);
        float inv = 1.0f / c;
        bf16x8 pv = *(const bf16x8*)&pooled[(size_t)rg * 128 + c8];
        bf16x8 hv, lv;
#pragma unroll
        for (int j = 0; j < 8; ++j) {
            float f = bf2f((unsigned short)pv[j]) * inv;
            unsigned short hh = f2bf(f);
            hv[j] = (short)hh;
            lv[j] = (short)f2bf(f - bf2f(hh));
        }
        int pc = row * 128 + (c8 ^ ((row & 7) << 3));
        *(bf16x8*)&Xh[pc] = hv;
        *(bf16x8*)&Xl[pc] = lv;
    }
    __syncthreads();

    f32x4 acc[2][2];
#pragma unroll
    for (int i = 0; i < 2; ++i) { acc[i][0] = (f32x4)0.0f; acc[i][1] = (f32x4)0.0f; }

#pragma unroll
    for (int kc = 0; kc < 4; ++kc) {
        bf16x8 ah[2], al[2];
#pragma unroll
        for (int rt = 0; rt < 2; ++rt) {
            int row = (rh * 2 + rt) * 16 + (l & 15);
            int col0 = kc * 32 + (l >> 4) * 8;
            int pc = row * 128 + (col0 ^ ((row & 7) << 3));
            ah[rt] = *(const bf16x8*)&Xh[pc];
            al[rt] = *(const bf16x8*)&Xl[pc];
        }
#pragma unroll
        for (int c2 = 0; c2 < 2; ++c2) {
            const int tile = kc * 8 + cg * 2 + c2;
            bf16x8 bh = *(const bf16x8*)&pk2a_h[(size_t)(tile * 64 + l) * 8];
            bf16x8 bl = *(const bf16x8*)&pk2a_l[(size_t)(tile * 64 + l) * 8];
#pragma unroll
            for (int rt = 0; rt < 2; ++rt) {
                acc[rt][c2] = MFMA(ah[rt], bh, acc[rt][c2], 0, 0, 0);
                acc[rt][c2] = MFMA(ah[rt], bl, acc[rt][c2], 0, 0, 0);
                acc[rt][c2] = MFMA(al[rt], bh, acc[rt][c2], 0, 0, 0);
            }
        }
    }
    __syncthreads();

#pragma unroll
    for (int c2 = 0; c2 < 2; ++c2) {
        int col = cg * 32 + c2 * 16 + (l & 15);
        float bb = b2a[col];
#pragma unroll
        for (int rt = 0; rt < 2; ++rt) {
#pragma unroll
            for (int r = 0; r < 4; ++r) {
                int row = (rh * 2 + rt) * 16 + (l >> 4) * 4 + r;
                float h = fmaxf(acc[rt][c2][r] + bb, 0.0f);
                unsigned short hh = f2bf(h);
                unsigned short hl = f2bf(h - bf2f(hh));
                int pc = row * 128 + (col ^ ((row & 7) << 3));
                Xh[pc] = hh; Xl[pc] = hl;
            }
        }
    }
    __syncthreads();

    f32x4 acc2[2][2];
#pragma unroll
    for (int i = 0; i < 2; ++i) { acc2[i][0] = (f32x4)0.0f; acc2[i][1] = (f32x4)0.0f; }

#pragma unroll
    for (int kc = 0; kc < 4; ++kc) {
        bf16x8 ah[2], al[2];
#pragma unroll
        for (int rt = 0; rt < 2; ++rt) {
            int row = (rh * 2 + rt) * 16 + (l & 15);
            int col0 = kc * 32 + (l >> 4) * 8;
            int pc = row * 128 + (col0 ^ ((row & 7) << 3));
            ah[rt] = *(const bf16x8*)&Xh[pc];
            al[rt] = *(const bf16x8*)&Xl[pc];
        }
#pragma unroll
        for (int c2 = 0; c2 < 2; ++c2) {
            const int tile = kc * 8 + cg * 2 + c2;
            bf16x8 bh = *(const bf16x8*)&pk2b_h[(size_t)(tile * 64 + l) * 8];
            bf16x8 bl = *(const bf16x8*)&pk2b_l[(size_t)(tile * 64 + l) * 8];
#pragma unroll
            for (int rt = 0; rt < 2; ++rt) {
                acc2[rt][c2] = MFMA(ah[rt], bh, acc2[rt][c2], 0, 0, 0);
                acc2[rt][c2] = MFMA(ah[rt], bl, acc2[rt][c2], 0, 0, 0);
                acc2[rt][c2] = MFMA(al[rt], bh, acc2[rt][c2], 0, 0, 0);
            }
        }
    }

#pragma unroll
    for (int c2 = 0; c2 < 2; ++c2) {
        int col = cg * 32 + c2 * 16 + (l & 15);
        float bb = b2b[col];
#pragma unroll
        for (int rt = 0; rt < 2; ++rt) {
#pragma unroll
            for (int r = 0; r < 4; ++r) {
                int row = (rh * 2 + rt) * 16 + (l >> 4) * 4 + r;
                if (r0 + row >= O) continue;
                float v = fmaxf(acc2[rt][c2][r] + bb, 0.0f);
                out[(size_t)(r0 + row) * 128 + col] = v;
            }
        }
    }
}

extern "C" void kernel_launch(void* const* d_in, const int* in_sizes, int n_in,
                              void* d_out, int out_size, void* d_ws, size_t ws_size,
                              hipStream_t stream) {
    const float* obj   = (const float*)d_in[0];
    const float* predi = (const float*)d_in[1];
    const int*   edges = (const int*)d_in[2];
    const float* w1a   = (const float*)d_in[3];
    const float* b1a   = (const float*)d_in[4];
    const float* w1b   = (const float*)d_in[5];
    const float* b1b   = (const float*)d_in[6];
    const float* w2a   = (const float*)d_in[7];
    const float* b2a   = (const float*)d_in[8];
    const float* w2b   = (const float*)d_in[9];
    const float* b2b   = (const float*)d_in[10];
    (void)n_in; (void)out_size; (void)ws_size;

    const int O = in_sizes[0] / 128;
    const int T = in_sizes[1] / 128;

    float* out     = (float*)d_out;
    float* new_obj = out;
    float* out_p   = out + (size_t)O * 128;

    // ws layout: counts(O f32) | pk(512*512 shorts) | pooled(O*128 bf16) | A_tb(O*256 bf16)
    float* counts = (float*)d_ws;
    unsigned short* pk     = (unsigned short*)(counts + O);
    unsigned short* pooled = pk + (size_t)512 * 512;
    unsigned short* A_tb   = pooled + (size_t)O * 128;

    unsigned short* pkc_h  = pk;
    unsigned short* pkc_l  = pkc_h  + 64 * 512;
    unsigned short* pkm_h  = pkc_l  + 64 * 512;
    unsigned short* pkm_l  = pkm_h  + 32 * 512;
    unsigned short* pk1b_h = pkm_l  + 32 * 512;
    unsigned short* pk1b_l = pk1b_h + 96 * 512;
    unsigned short* pk2a_h = pk1b_l + 96 * 512;
    unsigned short* pk2a_l = pk2a_h + 32 * 512;
    unsigned short* pk2b_h = pk2a_l + 32 * 512;
    unsigned short* pk2b_l = pk2b_h + 32 * 512;

    hipMemsetAsync(counts, 0, (size_t)O * sizeof(float), stream);
    hipMemsetAsync(pooled, 0, (size_t)O * 128 * sizeof(unsigned short), stream);

    pack_new<<<256, 64, 0, stream>>>(w1a, w1b, w2a, w2b, pk);
    obj_pre_kernel<<<(O + 63) / 64, 512, 0, stream>>>(obj, pkc_h, pkc_l, A_tb, O);
    triple_mlp_mfma2<<<(T + 63) / 64, 512, 0, stream>>>(
        A_tb, predi, edges, b1a, b1b,
        pkm_h, pkm_l, pk1b_h, pk1b_l,
        pooled, out_p, counts, T);
    obj_mlp_mfma<<<(O + 63) / 64, 512, 0, stream>>>(
        b2a, b2b, pk2a_h, pk2a_l, pk2b_h, pk2b_l, pooled, counts, new_obj, O);
}

// Round 6
// 962.777 us; speedup vs baseline: 1.4839x; 1.4839x over previous
//
#include <hip/hip_runtime.h>

typedef __attribute__((ext_vector_type(8))) short bf16x8;
typedef __attribute__((ext_vector_type(4))) float f32x4;
typedef __attribute__((ext_vector_type(4))) unsigned short u16x4;

#define MFMA __builtin_amdgcn_mfma_f32_16x16x32_bf16

__device__ __forceinline__ unsigned short f2bf(float x) {
    union { float f; unsigned u; } v; v.f = x;
    unsigned r = v.u + 0x7FFFu + ((v.u >> 16) & 1u);
    return (unsigned short)(r >> 16);
}
__device__ __forceinline__ float bf2f(unsigned short h) {
    union { unsigned u; float f; } v; v.u = ((unsigned)h) << 16;
    return v.f;
}
// packed bf16 atomic add, default device scope (L2-coherent, no write-through)
__device__ __forceinline__ void atom_pk_bf16(unsigned short* p, unsigned v2) {
    asm volatile("global_atomic_pk_add_bf16 %0, %1, off" :: "v"(p), "v"(v2) : "memory");
}

// ===========================================================================
// Pack weights into MFMA B-fragment layout, bf16 hi/lo.
// Regions (shorts): pkc_h(64*512) pkc_l | pkm_h(32*512) pkm_l |
//                   pk1b_h(96*512) pk1b_l | pk2a_h(32*512) pk2a_l |
//                   pk2b_h(32*512) pk2b_l      (total 512*512 shorts = 512KB)
// ===========================================================================
__global__ void pack_new(const float* __restrict__ w1a, const float* __restrict__ w1b,
                         const float* __restrict__ w2a, const float* __restrict__ w2b,
                         unsigned short* __restrict__ pk)
{
    const int b = blockIdx.x, l = threadIdx.x;
    unsigned short* ph;
    unsigned short* pl;
    int tile;
    bf16x8 hv, lv;

    if (b < 64) {            // cat: [W_top | W_bot], 4kc x 16ct
        tile = b;
        ph = pk; pl = pk + 64 * 512;
        int kc = tile >> 4, ct = tile & 15;
#pragma unroll
        for (int j = 0; j < 8; ++j) {
            int k = kc * 32 + (l >> 4) * 8 + j;
            int n = ct * 16 + (l & 15);
            float v = (n < 128) ? w1a[(size_t)k * 128 + n]
                                : w1a[(size_t)(256 + k) * 128 + (n - 128)];
            unsigned short h = f2bf(v);
            hv[j] = (short)h; lv[j] = (short)f2bf(v - bf2f(h));
        }
    } else if (b < 96) {     // mid: 4kc x 8ct
        tile = b - 64;
        ph = pk + 2 * 64 * 512; pl = ph + 32 * 512;
        int kc = tile >> 3, ct = tile & 7;
#pragma unroll
        for (int j = 0; j < 8; ++j) {
            int k = kc * 32 + (l >> 4) * 8 + j;
            int n = ct * 16 + (l & 15);
            float v = w1a[(size_t)(128 + k) * 128 + n];
            unsigned short h = f2bf(v);
            hv[j] = (short)h; lv[j] = (short)f2bf(v - bf2f(h));
        }
    } else if (b < 192) {    // w1b: 4kc x 24ct
        tile = b - 96;
        ph = pk + 2 * 64 * 512 + 2 * 32 * 512; pl = ph + 96 * 512;
        int kc = tile / 24, ct = tile % 24;
#pragma unroll
        for (int j = 0; j < 8; ++j) {
            int k = kc * 32 + (l >> 4) * 8 + j;
            int n = ct * 16 + (l & 15);
            float v = w1b[(size_t)k * 384 + n];
            unsigned short h = f2bf(v);
            hv[j] = (short)h; lv[j] = (short)f2bf(v - bf2f(h));
        }
    } else if (b < 224) {    // w2a
        tile = b - 192;
        ph = pk + 2 * 64 * 512 + 2 * 32 * 512 + 2 * 96 * 512; pl = ph + 32 * 512;
        int kc = tile >> 3, ct = tile & 7;
#pragma unroll
        for (int j = 0; j < 8; ++j) {
            int k = kc * 32 + (l >> 4) * 8 + j;
            int n = ct * 16 + (l & 15);
            float v = w2a[(size_t)k * 128 + n];
            unsigned short h = f2bf(v);
            hv[j] = (short)h; lv[j] = (short)f2bf(v - bf2f(h));
        }
    } else {                 // w2b
        tile = b - 224;
        ph = pk + 2 * 64 * 512 + 2 * 32 * 512 + 2 * 96 * 512 + 2 * 32 * 512; pl = ph + 32 * 512;
        int kc = tile >> 3, ct = tile & 7;
#pragma unroll
        for (int j = 0; j < 8; ++j) {
            int k = kc * 32 + (l >> 4) * 8 + j;
            int n = ct * 16 + (l & 15);
            float v = w2b[(size_t)k * 128 + n];
            unsigned short h = f2bf(v);
            hv[j] = (short)h; lv[j] = (short)f2bf(v - bf2f(h));
        }
    }
    *(bf16x8*)&ph[(size_t)(tile * 64 + l) * 8] = hv;
    *(bf16x8*)&pl[(size_t)(tile * 64 + l) * 8] = lv;
}

// ===========================================================================
// Precompute A_tb = obj @ [W_top | W_bot]  (O x 256, stored BF16).
// ===========================================================================
__global__ __launch_bounds__(512, 4) void obj_pre_kernel(
    const float* __restrict__ obj,
    const unsigned short* __restrict__ pkc_h, const unsigned short* __restrict__ pkc_l,
    unsigned short* __restrict__ A_tb, int O)
{
    __shared__ __align__(16) unsigned short Xh[64 * 128];
    __shared__ __align__(16) unsigned short Xl[64 * 128];

    const int tid = threadIdx.x;
    const int w = tid >> 6, l = tid & 63;
    const int rh = w & 1, cg = w >> 1;
    const int r0 = blockIdx.x * 64;

#pragma unroll
    for (int it = 0; it < 4; ++it) {
        int q = it * 512 + tid;
        int row = q >> 5, c4 = (q & 31) * 4;
        int rg = r0 + row; if (rg > O - 1) rg = O - 1;
        float4 v = *(const float4*)&obj[(size_t)rg * 128 + c4];
        u16x4 hv, lv; unsigned short h;
        h = f2bf(v.x); hv[0] = h; lv[0] = f2bf(v.x - bf2f(h));
        h = f2bf(v.y); hv[1] = h; lv[1] = f2bf(v.y - bf2f(h));
        h = f2bf(v.z); hv[2] = h; lv[2] = f2bf(v.z - bf2f(h));
        h = f2bf(v.w); hv[3] = h; lv[3] = f2bf(v.w - bf2f(h));
        int pc = row * 128 + (c4 ^ ((row & 7) << 3));
        *(u16x4*)&Xh[pc] = hv;
        *(u16x4*)&Xl[pc] = lv;
    }
    __syncthreads();

    f32x4 acc[2][4];
#pragma unroll
    for (int i = 0; i < 2; ++i)
#pragma unroll
        for (int j = 0; j < 4; ++j) acc[i][j] = (f32x4)0.0f;

#pragma unroll
    for (int kc = 0; kc < 4; ++kc) {
        bf16x8 ah[2], al[2];
#pragma unroll
        for (int rt = 0; rt < 2; ++rt) {
            int row = (rh * 2 + rt) * 16 + (l & 15);
            int col0 = kc * 32 + (l >> 4) * 8;
            int pc = row * 128 + (col0 ^ ((row & 7) << 3));
            ah[rt] = *(const bf16x8*)&Xh[pc];
            al[rt] = *(const bf16x8*)&Xl[pc];
        }
#pragma unroll
        for (int ct = 0; ct < 4; ++ct) {
            const int tile = kc * 16 + cg * 4 + ct;
            bf16x8 bh = *(const bf16x8*)&pkc_h[(size_t)(tile * 64 + l) * 8];
            bf16x8 bl = *(const bf16x8*)&pkc_l[(size_t)(tile * 64 + l) * 8];
#pragma unroll
            for (int rt = 0; rt < 2; ++rt) {
                acc[rt][ct] = MFMA(ah[rt], bh, acc[rt][ct], 0, 0, 0);
                acc[rt][ct] = MFMA(ah[rt], bl, acc[rt][ct], 0, 0, 0);
                acc[rt][ct] = MFMA(al[rt], bh, acc[rt][ct], 0, 0, 0);
            }
        }
    }

    // store bf16, lane-pair packed into dwords
#pragma unroll
    for (int ct = 0; ct < 4; ++ct) {
        int col = cg * 64 + ct * 16 + (l & 15);
        int cb = col & ~1;
#pragma unroll
        for (int rt = 0; rt < 2; ++rt) {
            float v[4], p[4];
#pragma unroll
            for (int r = 0; r < 4; ++r) v[r] = acc[rt][ct][r];
#pragma unroll
            for (int r = 0; r < 4; ++r) p[r] = __shfl_xor(v[r], 1, 64);
            int base = (rh * 2 + rt) * 16 + (l >> 4) * 4;
#pragma unroll
            for (int k = 0; k < 2; ++k) {
                int rr = (l & 1) * 2 + k;
                int row = base + rr;
                float lo = (l & 1) ? p[rr] : v[rr];
                float hi = (l & 1) ? v[rr] : p[rr];
                unsigned u = (unsigned)f2bf(lo) | ((unsigned)f2bf(hi) << 16);
                if (r0 + row < O)
                    *(unsigned*)&A_tb[(size_t)(r0 + row) * 256 + cb] = u;
            }
        }
    }
}

// ===========================================================================
// Triple kernel: G = A_top[s]+A_bot[o]+b1a -> acc init; GEMM1 = predi@W_mid;
// GEMM2; scatter via packed-bf16 atomics (device scope) to pooled (bf16).
// ===========================================================================
__global__ __launch_bounds__(512, 4) void triple_mlp_mfma2(
    const unsigned short* __restrict__ A_tb, const float* __restrict__ predi,
    const int* __restrict__ edges,
    const float* __restrict__ b1a, const float* __restrict__ b1b,
    const unsigned short* __restrict__ pkm_h, const unsigned short* __restrict__ pkm_l,
    const unsigned short* __restrict__ pk1b_h, const unsigned short* __restrict__ pk1b_l,
    unsigned short* __restrict__ pooled, float* __restrict__ out_p,
    float* __restrict__ counts, int T)
{
    __shared__ __align__(16) char SB[64 * 132 * 4];
    float (*G)[132] = (float (*)[132])SB;
    unsigned short* Xh = (unsigned short*)SB;
    unsigned short* Xl = (unsigned short*)(SB + 64 * 128 * 2);
    __shared__ int sIdx[64], oIdx[64];

    const int tid = threadIdx.x;
    const int w = tid >> 6, l = tid & 63;
    const int rh = w & 1, cg = w >> 1;
    const int t0 = blockIdx.x * 64;

    if (tid < 64) {
        int t = t0 + tid; int tc = (t < T) ? t : (T - 1);
        sIdx[tid] = edges[2 * tc];
        oIdx[tid] = edges[2 * tc + 1];
    }
    __syncthreads();

    if (tid < 64)        { if (t0 + tid      < T) atomicAdd(&counts[sIdx[tid]],      1.0f); }
    else if (tid < 128)  { if (t0 + tid - 64 < T) atomicAdd(&counts[oIdx[tid - 64]], 1.0f); }

    // ---- stage G = A_top[s] + A_bot[o] + b1a (f32, pad 132) ----
#pragma unroll
    for (int it = 0; it < 2; ++it) {
        int q = it * 512 + tid;
        int row = q >> 4, c8 = (q & 15) * 8;
        bf16x8 a = *(const bf16x8*)&A_tb[(size_t)sIdx[row] * 256 + c8];
        bf16x8 b = *(const bf16x8*)&A_tb[(size_t)oIdx[row] * 256 + 128 + c8];
        float bb[8];
        *(float4*)&bb[0] = *(const float4*)&b1a[c8];
        *(float4*)&bb[4] = *(const float4*)&b1a[c8 + 4];
        float g[8];
#pragma unroll
        for (int j = 0; j < 8; ++j)
            g[j] = bf2f((unsigned short)a[j]) + bf2f((unsigned short)b[j]) + bb[j];
        *(float4*)&G[row][c8]     = *(float4*)&g[0];
        *(float4*)&G[row][c8 + 4] = *(float4*)&g[4];
    }
    __syncthreads();

    // ---- init acc1 from G (C-fragment layout) ----
    f32x4 acc1[2][2];
#pragma unroll
    for (int rt = 0; rt < 2; ++rt)
#pragma unroll
        for (int c2 = 0; c2 < 2; ++c2) {
            int col = cg * 32 + c2 * 16 + (l & 15);
#pragma unroll
            for (int r = 0; r < 4; ++r) {
                int row = (rh * 2 + rt) * 16 + (l >> 4) * 4 + r;
                acc1[rt][c2][r] = G[row][col];
            }
        }
    __syncthreads();   // G dead; Xh/Xl reuse same LDS

    // ---- stage predi -> Xh/Xl (bf16 hi/lo, swizzled) ----
#pragma unroll
    for (int it = 0; it < 4; ++it) {
        int q = it * 512 + tid;
        int row = q >> 5, c4 = (q & 31) * 4;
        int t = t0 + row; int tc = (t < T) ? t : (T - 1);
        float4 v = *(const float4*)&predi[(size_t)tc * 128 + c4];
        u16x4 hv, lv; unsigned short h;
        h = f2bf(v.x); hv[0] = h; lv[0] = f2bf(v.x - bf2f(h));
        h = f2bf(v.y); hv[1] = h; lv[1] = f2bf(v.y - bf2f(h));
        h = f2bf(v.z); hv[2] = h; lv[2] = f2bf(v.z - bf2f(h));
        h = f2bf(v.w); hv[3] = h; lv[3] = f2bf(v.w - bf2f(h));
        int pc = row * 128 + (c4 ^ ((row & 7) << 3));
        *(u16x4*)&Xh[pc] = hv;
        *(u16x4*)&Xl[pc] = lv;
    }
    __syncthreads();

    // ---- GEMM1: acc1 += predi @ W_mid ----
#pragma unroll
    for (int kc = 0; kc < 4; ++kc) {
        bf16x8 ah[2], al[2];
#pragma unroll
        for (int rt = 0; rt < 2; ++rt) {
            int row = (rh * 2 + rt) * 16 + (l & 15);
            int col0 = kc * 32 + (l >> 4) * 8;
            int pc = row * 128 + (col0 ^ ((row & 7) << 3));
            ah[rt] = *(const bf16x8*)&Xh[pc];
            al[rt] = *(const bf16x8*)&Xl[pc];
        }
#pragma unroll
        for (int c2 = 0; c2 < 2; ++c2) {
            const int tile = kc * 8 + cg * 2 + c2;
            bf16x8 bh = *(const bf16x8*)&pkm_h[(size_t)(tile * 64 + l) * 8];
            bf16x8 bl = *(const bf16x8*)&pkm_l[(size_t)(tile * 64 + l) * 8];
#pragma unroll
            for (int rt = 0; rt < 2; ++rt) {
                acc1[rt][c2] = MFMA(ah[rt], bh, acc1[rt][c2], 0, 0, 0);
                acc1[rt][c2] = MFMA(ah[rt], bl, acc1[rt][c2], 0, 0, 0);
                acc1[rt][c2] = MFMA(al[rt], bh, acc1[rt][c2], 0, 0, 0);
            }
        }
    }
    __syncthreads();

    // ---- H = relu(acc1) -> Xh/Xl ----
#pragma unroll
    for (int c2 = 0; c2 < 2; ++c2) {
        int col = cg * 32 + c2 * 16 + (l & 15);
#pragma unroll
        for (int rt = 0; rt < 2; ++rt) {
#pragma unroll
            for (int r = 0; r < 4; ++r) {
                int row = (rh * 2 + rt) * 16 + (l >> 4) * 4 + r;
                float h = fmaxf(acc1[rt][c2][r], 0.0f);
                unsigned short hh = f2bf(h);
                unsigned short hl = f2bf(h - bf2f(hh));
                int pc = row * 128 + (col ^ ((row & 7) << 3));
                Xh[pc] = hh; Xl[pc] = hl;
            }
        }
    }
    __syncthreads();

    // ---- GEMM2: H @ w1b (128x384) ----
    f32x4 acc2[2][6];
#pragma unroll
    for (int i = 0; i < 2; ++i)
#pragma unroll
        for (int j = 0; j < 6; ++j) acc2[i][j] = (f32x4)0.0f;

#pragma unroll
    for (int kc = 0; kc < 4; ++kc) {
        bf16x8 ah[2], al[2];
#pragma unroll
        for (int rt = 0; rt < 2; ++rt) {
            int row = (rh * 2 + rt) * 16 + (l & 15);
            int col0 = kc * 32 + (l >> 4) * 8;
            int pc = row * 128 + (col0 ^ ((row & 7) << 3));
            ah[rt] = *(const bf16x8*)&Xh[pc];
            al[rt] = *(const bf16x8*)&Xl[pc];
        }
#pragma unroll
        for (int ct = 0; ct < 6; ++ct) {
            const int tile = kc * 24 + cg * 6 + ct;
            bf16x8 bh = *(const bf16x8*)&pk1b_h[(size_t)(tile * 64 + l) * 8];
            bf16x8 bl = *(const bf16x8*)&pk1b_l[(size_t)(tile * 64 + l) * 8];
#pragma unroll
            for (int rt = 0; rt < 2; ++rt) {
                acc2[rt][ct] = MFMA(ah[rt], bh, acc2[rt][ct], 0, 0, 0);
                acc2[rt][ct] = MFMA(ah[rt], bl, acc2[rt][ct], 0, 0, 0);
                acc2[rt][ct] = MFMA(al[rt], bh, acc2[rt][ct], 0, 0, 0);
            }
        }
    }

    // ---- epilogue: cols 0-127 -> pk-atomic s, 128-255 -> new_p, 256-383 -> pk-atomic o
#pragma unroll
    for (int ct = 0; ct < 6; ++ct) {
        int col = cg * 96 + ct * 16 + (l & 15);
        float bb = b1b[col];
#pragma unroll
        for (int rt = 0; rt < 2; ++rt) {
            float v[4];
#pragma unroll
            for (int r = 0; r < 4; ++r) v[r] = fmaxf(acc2[rt][ct][r] + bb, 0.0f);
            int base = (rh * 2 + rt) * 16 + (l >> 4) * 4;
            if (col >= 128 && col < 256) {
#pragma unroll
                for (int r = 0; r < 4; ++r) {
                    int row = base + r;
                    if (t0 + row < T)
                        out_p[(size_t)(t0 + row) * 128 + (col - 128)] = v[r];
                }
            } else {
                float p[4];
#pragma unroll
                for (int r = 0; r < 4; ++r) p[r] = __shfl_xor(v[r], 1, 64);
                const int* IDX = (col < 128) ? sIdx : oIdx;
                int cb = ((col < 128) ? col : col - 256) & ~1;
#pragma unroll
                for (int k = 0; k < 2; ++k) {
                    int rr = (l & 1) * 2 + k;
                    int row = base + rr;
                    float lo = (l & 1) ? p[rr] : v[rr];
                    float hi = (l & 1) ? v[rr] : p[rr];
                    unsigned u = (unsigned)f2bf(lo) | ((unsigned)f2bf(hi) << 16);
                    if (t0 + row < T)
                        atom_pk_bf16(pooled + (size_t)IDX[row] * 128 + cb, u);
                }
            }
        }
    }
}

// ===========================================================================
// Object MLP: reads pooled (bf16) / counts, writes new_obj (f32) to d_out.
// ===========================================================================
__global__ __launch_bounds__(512, 4) void obj_mlp_mfma(
    const float* __restrict__ b2a, const float* __restrict__ b2b,
    const unsigned short* __restrict__ pk2a_h, const unsigned short* __restrict__ pk2a_l,
    const unsigned short* __restrict__ pk2b_h, const unsigned short* __restrict__ pk2b_l,
    const unsigned short* __restrict__ pooled, const float* __restrict__ counts,
    float* __restrict__ out, int O)
{
    __shared__ __align__(16) unsigned short Xh[64 * 128];
    __shared__ __align__(16) unsigned short Xl[64 * 128];

    const int tid = threadIdx.x;
    const int w = tid >> 6, l = tid & 63;
    const int rh = w & 1, cg = w >> 1;
    const int r0 = blockIdx.x * 64;

    // stage pooled(bf16)/counts -> normalized x, hi/lo swizzled
#pragma unroll
    for (int it = 0; it < 2; ++it) {
        int q = it * 512 + tid;
        int row = q >> 4, c8 = (q & 15) * 8;
        int rg = r0 + row; if (rg > O - 1) rg = O - 1;
        float c = counts[rg];
        c = fminf(fmaxf(c, 1.0f), 1000.0f);
        float inv = 1.0f / c;
        bf16x8 pv = *(const bf16x8*)&pooled[(size_t)rg * 128 + c8];
        bf16x8 hv, lv;
#pragma unroll
        for (int j = 0; j < 8; ++j) {
            float f = bf2f((unsigned short)pv[j]) * inv;
            unsigned short hh = f2bf(f);
            hv[j] = (short)hh;
            lv[j] = (short)f2bf(f - bf2f(hh));
        }
        int pc = row * 128 + (c8 ^ ((row & 7) << 3));
        *(bf16x8*)&Xh[pc] = hv;
        *(bf16x8*)&Xl[pc] = lv;
    }
    __syncthreads();

    f32x4 acc[2][2];
#pragma unroll
    for (int i = 0; i < 2; ++i) { acc[i][0] = (f32x4)0.0f; acc[i][1] = (f32x4)0.0f; }

#pragma unroll
    for (int kc = 0; kc < 4; ++kc) {
        bf16x8 ah[2], al[2];
#pragma unroll
        for (int rt = 0; rt < 2; ++rt) {
            int row = (rh * 2 + rt) * 16 + (l & 15);
            int col0 = kc * 32 + (l >> 4) * 8;
            int pc = row * 128 + (col0 ^ ((row & 7) << 3));
            ah[rt] = *(const bf16x8*)&Xh[pc];
            al[rt] = *(const bf16x8*)&Xl[pc];
        }
#pragma unroll
        for (int c2 = 0; c2 < 2; ++c2) {
            const int tile = kc * 8 + cg * 2 + c2;
            bf16x8 bh = *(const bf16x8*)&pk2a_h[(size_t)(tile * 64 + l) * 8];
            bf16x8 bl = *(const bf16x8*)&pk2a_l[(size_t)(tile * 64 + l) * 8];
#pragma unroll
            for (int rt = 0; rt < 2; ++rt) {
                acc[rt][c2] = MFMA(ah[rt], bh, acc[rt][c2], 0, 0, 0);
                acc[rt][c2] = MFMA(ah[rt], bl, acc[rt][c2], 0, 0, 0);
                acc[rt][c2] = MFMA(al[rt], bh, acc[rt][c2], 0, 0, 0);
            }
        }
    }
    __syncthreads();

#pragma unroll
    for (int c2 = 0; c2 < 2; ++c2) {
        int col = cg * 32 + c2 * 16 + (l & 15);
        float bb = b2a[col];
#pragma unroll
        for (int rt = 0; rt < 2; ++rt) {
#pragma unroll
            for (int r = 0; r < 4; ++r) {
                int row = (rh * 2 + rt) * 16 + (l >> 4) * 4 + r;
                float h = fmaxf(acc[rt][c2][r] + bb, 0.0f);
                unsigned short hh = f2bf(h);
                unsigned short hl = f2bf(h - bf2f(hh));
                int pc = row * 128 + (col ^ ((row & 7) << 3));
                Xh[pc] = hh; Xl[pc] = hl;
            }
        }
    }
    __syncthreads();

    f32x4 acc2[2][2];
#pragma unroll
    for (int i = 0; i < 2; ++i) { acc2[i][0] = (f32x4)0.0f; acc2[i][1] = (f32x4)0.0f; }

#pragma unroll
    for (int kc = 0; kc < 4; ++kc) {
        bf16x8 ah[2], al[2];
#pragma unroll
        for (int rt = 0; rt < 2; ++rt) {
            int row = (rh * 2 + rt) * 16 + (l & 15);
            int col0 = kc * 32 + (l >> 4) * 8;
            int pc = row * 128 + (col0 ^ ((row & 7) << 3));
            ah[rt] = *(const bf16x8*)&Xh[pc];
            al[rt] = *(const bf16x8*)&Xl[pc];
        }
#pragma unroll
        for (int c2 = 0; c2 < 2; ++c2) {
            const int tile = kc * 8 + cg * 2 + c2;
            bf16x8 bh = *(const bf16x8*)&pk2b_h[(size_t)(tile * 64 + l) * 8];
            bf16x8 bl = *(const bf16x8*)&pk2b_l[(size_t)(tile * 64 + l) * 8];
#pragma unroll
            for (int rt = 0; rt < 2; ++rt) {
                acc2[rt][c2] = MFMA(ah[rt], bh, acc2[rt][c2], 0, 0, 0);
                acc2[rt][c2] = MFMA(ah[rt], bl, acc2[rt][c2], 0, 0, 0);
                acc2[rt][c2] = MFMA(al[rt], bh, acc2[rt][c2], 0, 0, 0);
            }
        }
    }

#pragma unroll
    for (int c2 = 0; c2 < 2; ++c2) {
        int col = cg * 32 + c2 * 16 + (l & 15);
        float bb = b2b[col];
#pragma unroll
        for (int rt = 0; rt < 2; ++rt) {
#pragma unroll
            for (int r = 0; r < 4; ++r) {
                int row = (rh * 2 + rt) * 16 + (l >> 4) * 4 + r;
                if (r0 + row >= O) continue;
                float v = fmaxf(acc2[rt][c2][r] + bb, 0.0f);
                out[(size_t)(r0 + row) * 128 + col] = v;
            }
        }
    }
}

extern "C" void kernel_launch(void* const* d_in, const int* in_sizes, int n_in,
                              void* d_out, int out_size, void* d_ws, size_t ws_size,
                              hipStream_t stream) {
    const float* obj   = (const float*)d_in[0];
    const float* predi = (const float*)d_in[1];
    const int*   edges = (const int*)d_in[2];
    const float* w1a   = (const float*)d_in[3];
    const float* b1a   = (const float*)d_in[4];
    const float* w1b   = (const float*)d_in[5];
    const float* b1b   = (const float*)d_in[6];
    const float* w2a   = (const float*)d_in[7];
    const float* b2a   = (const float*)d_in[8];
    const float* w2b   = (const float*)d_in[9];
    const float* b2b   = (const float*)d_in[10];
    (void)n_in; (void)out_size; (void)ws_size;

    const int O = in_sizes[0] / 128;
    const int T = in_sizes[1] / 128;

    float* out     = (float*)d_out;
    float* new_obj = out;
    float* out_p   = out + (size_t)O * 128;

    // ws layout: counts(O f32) | pk(512*512 shorts) | pooled(O*128 bf16) | A_tb(O*256 bf16)
    float* counts = (float*)d_ws;
    unsigned short* pk     = (unsigned short*)(counts + O);
    unsigned short* pooled = pk + (size_t)512 * 512;
    unsigned short* A_tb   = pooled + (size_t)O * 128;

    unsigned short* pkc_h  = pk;
    unsigned short* pkc_l  = pkc_h  + 64 * 512;
    unsigned short* pkm_h  = pkc_l  + 64 * 512;
    unsigned short* pkm_l  = pkm_h  + 32 * 512;
    unsigned short* pk1b_h = pkm_l  + 32 * 512;
    unsigned short* pk1b_l = pk1b_h + 96 * 512;
    unsigned short* pk2a_h = pk1b_l + 96 * 512;
    unsigned short* pk2a_l = pk2a_h + 32 * 512;
    unsigned short* pk2b_h = pk2a_l + 32 * 512;
    unsigned short* pk2b_l = pk2b_h + 32 * 512;

    hipMemsetAsync(counts, 0, (size_t)O * sizeof(float), stream);
    hipMemsetAsync(pooled, 0, (size_t)O * 128 * sizeof(unsigned short), stream);

    pack_new<<<256, 64, 0, stream>>>(w1a, w1b, w2a, w2b, pk);
    obj_pre_kernel<<<(O + 63) / 64, 512, 0, stream>>>(obj, pkc_h, pkc_l, A_tb, O);
    triple_mlp_mfma2<<<(T + 63) / 64, 512, 0, stream>>>(
        A_tb, predi, edges, b1a, b1b,
        pkm_h, pkm_l, pk1b_h, pk1b_l,
        pooled, out_p, counts, T);
    obj_mlp_mfma<<<(O + 63) / 64, 512, 0, stream>>>(
        b2a, b2b, pk2a_h, pk2a_l, pk2b_h, pk2b_l, pooled, counts, new_obj, O);
}